// Round 1
// 410.658 us; speedup vs baseline: 1.0138x; 1.0138x over previous
//
#include <hip/hip_runtime.h>
#include <hip/hip_bf16.h>

#define NB 16
#define NP 1024
#define CF 768
#define CC 512
#define HH 28
#define WW 28
#define HW 784
#define NTOT 16777216.0f  // 16*1024*1024

typedef float f32x4 __attribute__((ext_vector_type(4)));
struct __align__(8) bf4 { __hip_bfloat16 a, b, c, d; };

__device__ __forceinline__ float b2f(__hip_bfloat16 h) { return __bfloat162float(h); }

// Supertile layout (UNSCALED fp8 e4m3; norms applied in corr epilogue):
//   feats: [slot(4)][b(16)][kt(12)][pt(8)] x 1024 chunks of 8B,
//   code : [slot(4)][b(16)][kt(8) ][pt(8)] x 1024 chunks of 8B,
// chunk index = r*128 + m (r in [0,8), m = p&127), payload = 8 fp8 =
// channels [kt*64 + r*8 .. +8) of position row p -- exactly the LDS image
// corr_kernel's MFMA ds_reads consume (fp8 16x16x32 A/B frag: lane%16 = row,
// k = (lane/16)*8 + byte, same structure as the verified bf16 variant).
// Staging is a contiguous 8 KB stream per supertile. Norm scales scF/scC
// f32, applied as rank-1 diag in the corr epilogue (relu commutes with
// positive scales; fp8 rounding is RNE -> unbiased).

// ---------------------------------------------------------------- transpose
// (B, C, HW) f32 -> [t(2)][b][HW][C] bf16. z encodes t (self/pos) and batch.
__global__ void transpose_bf16_kernel(const float* __restrict__ in0,
                                      const float* __restrict__ in1,
                                      __hip_bfloat16* __restrict__ out, int C) {
  __shared__ float tile[32][33];
  int p0 = blockIdx.x * 32, c0 = blockIdx.y * 32;
  int t = blockIdx.z >> 4, b = blockIdx.z & 15;
  int tx = threadIdx.x, ty = threadIdx.y;
  const float* ib = (t == 0 ? in0 : in1) + (size_t)b * C * HW;
  __hip_bfloat16* ob = out + ((size_t)t * NB + b) * HW * C;
#pragma unroll
  for (int i = 0; i < 32; i += 8) {
    int c = c0 + ty + i, p = p0 + tx;
    if (p < HW) tile[ty + i][tx] = ib[(size_t)c * HW + p];
  }
  __syncthreads();
#pragma unroll
  for (int i = 0; i < 32; i += 8) {
    int p = p0 + ty + i, c = c0 + tx;
    if (p < HW) ob[(size_t)p * C + c] = __float2bfloat16(tile[tx][ty + i]);
  }
}

// ---------------------------------------------------------------- sampling
// One launch, grid (16,16,4): x = 64-position block, y = batch, z = slot.
// slot 0: coords1/self, 1: coords2/pos-tensors, 2,3: coords2/neg (permuted).
// 256 threads = 16 groups x 16 lanes. Per kt-slice (64ch): group g handles
// positions j*16+g, lane l gathers bf16x4 of 4 corners (128B-contig
// segments), combines in f32, accumulates ssq, packs fp8 via
// v_cvt_pk_fp8_f32 into an LDS supertile image, block flushes 4 KB
// fully-coalesced. End: write 1/norm.
__global__ __launch_bounds__(256) void sample_pack_kernel(
    const __hip_bfloat16* __restrict__ fTb, const __hip_bfloat16* __restrict__ cTb,
    const float* __restrict__ coords1, const float* __restrict__ coords2,
    const int* __restrict__ perms,
    unsigned char* __restrict__ Fb, unsigned char* __restrict__ Cb,
    float* __restrict__ scF, float* __restrict__ scC) {
  __shared__ int offs[4][64];
  __shared__ float wts[4][64];
  __shared__ char tile[4160];  // 8 r-rows x (64 chunks*8B + 8B pad)

  int bb = blockIdx.y, slot = blockIdx.z;
  int tid = threadIdx.x;
  int p0 = blockIdx.x * 64;
  int pt = blockIdx.x >> 1, mh = blockIdx.x & 1;

  const float* coords = (slot == 0) ? coords1 : coords2;
  int srcidx;  // index into [t(2)][b(16)] transposed buffers
  if (slot == 0)      srcidx = bb;
  else if (slot == 1) srcidx = 16 + bb;
  else if (slot == 2) srcidx = perms[bb];
  else                srcidx = perms[16 + bb];

  if (tid < 64) {
    int p = p0 + tid;
    float cx = coords[((size_t)bb * NP + p) * 2 + 0];
    float cy = coords[((size_t)bb * NP + p) * 2 + 1];
    float x = cx * (WW - 1), y = cy * (HH - 1);  // (c*2-1 +1)*0.5*(W-1)
    float x0f = floorf(x), y0f = floorf(y);
    float wx = x - x0f, wy = y - y0f;
    int x0 = min(max((int)x0f, 0), WW - 1);
    int x1 = min(max((int)x0f + 1, 0), WW - 1);
    int y0 = min(max((int)y0f, 0), HH - 1);
    int y1 = min(max((int)y0f + 1, 0), HH - 1);
    offs[0][tid] = y0 * WW + x0;
    offs[1][tid] = y1 * WW + x0;
    offs[2][tid] = y0 * WW + x1;
    offs[3][tid] = y1 * WW + x1;
    wts[0][tid] = (1.f - wx) * (1.f - wy);
    wts[1][tid] = (1.f - wx) * wy;
    wts[2][tid] = wx * (1.f - wy);
    wts[3][tid] = wx * wy;
  }
  __syncthreads();

  int gid = tid >> 4, l = tid & 15;
  int r = l >> 1, h4 = l & 1;

  // ---------------- feats (12 kt-slices)
  {
    const __hip_bfloat16* base = fTb + (size_t)srcidx * HW * CF;
    float ssq[4] = {0.f, 0.f, 0.f, 0.f};
    for (int kt = 0; kt < 12; ++kt) {
#pragma unroll
      for (int j = 0; j < 4; ++j) {
        int m = j * 16 + gid;
        float4 v = {0.f, 0.f, 0.f, 0.f};
#pragma unroll
        for (int c = 0; c < 4; ++c) {
          const bf4 t4 = *((const bf4*)(base + (size_t)offs[c][m] * CF) + kt * 16 + l);
          float wv = wts[c][m];
          v.x += wv * b2f(t4.a); v.y += wv * b2f(t4.b);
          v.z += wv * b2f(t4.c); v.w += wv * b2f(t4.d);
        }
        ssq[j] += v.x * v.x + v.y * v.y + v.z * v.z + v.w * v.w;
        int w0 = __builtin_amdgcn_cvt_pk_fp8_f32(v.x, v.y, 0, false);
        int w1 = __builtin_amdgcn_cvt_pk_fp8_f32(v.z, v.w, w0, true);
        *(int*)(tile + r * 520 + m * 8 + h4 * 4) = w1;
      }
      __syncthreads();
      unsigned char* gbase = Fb +
          (((((size_t)slot * NB + bb) * 12 + kt) * 8 + pt) * 1024 + (size_t)mh * 64) * 8;
#pragma unroll
      for (int jj = 0; jj < 2; ++jj) {
        int cl = jj * 256 + tid;
        int rr = cl >> 6, mi = cl & 63;
        unsigned long long val = *(const unsigned long long*)(tile + rr * 520 + mi * 8);
        *(unsigned long long*)(gbase + (size_t)(rr * 128 + mi) * 8) = val;
      }
      __syncthreads();
    }
#pragma unroll
    for (int j = 0; j < 4; ++j) {
#pragma unroll
      for (int mm = 1; mm < 16; mm <<= 1) ssq[j] += __shfl_xor(ssq[j], mm);
    }
    if (l == 0) {
#pragma unroll
      for (int j = 0; j < 4; ++j) {
        int p = p0 + j * 16 + gid;
        scF[((size_t)slot * NB + bb) * NP + p] = 1.f / fmaxf(sqrtf(ssq[j]), 1e-10f);
      }
    }
  }

  // ---------------- code (8 kt-slices)
  {
    const __hip_bfloat16* base = cTb + (size_t)srcidx * HW * CC;
    float ssq[4] = {0.f, 0.f, 0.f, 0.f};
    for (int kt = 0; kt < 8; ++kt) {
#pragma unroll
      for (int j = 0; j < 4; ++j) {
        int m = j * 16 + gid;
        float4 v = {0.f, 0.f, 0.f, 0.f};
#pragma unroll
        for (int c = 0; c < 4; ++c) {
          const bf4 t4 = *((const bf4*)(base + (size_t)offs[c][m] * CC) + kt * 16 + l);
          float wv = wts[c][m];
          v.x += wv * b2f(t4.a); v.y += wv * b2f(t4.b);
          v.z += wv * b2f(t4.c); v.w += wv * b2f(t4.d);
        }
        ssq[j] += v.x * v.x + v.y * v.y + v.z * v.z + v.w * v.w;
        int w0 = __builtin_amdgcn_cvt_pk_fp8_f32(v.x, v.y, 0, false);
        int w1 = __builtin_amdgcn_cvt_pk_fp8_f32(v.z, v.w, w0, true);
        *(int*)(tile + r * 520 + m * 8 + h4 * 4) = w1;
      }
      __syncthreads();
      unsigned char* gbase = Cb +
          (((((size_t)slot * NB + bb) * 8 + kt) * 8 + pt) * 1024 + (size_t)mh * 64) * 8;
#pragma unroll
      for (int jj = 0; jj < 2; ++jj) {
        int cl = jj * 256 + tid;
        int rr = cl >> 6, mi = cl & 63;
        unsigned long long val = *(const unsigned long long*)(tile + rr * 520 + mi * 8);
        *(unsigned long long*)(gbase + (size_t)(rr * 128 + mi) * 8) = val;
      }
      __syncthreads();
    }
#pragma unroll
    for (int j = 0; j < 4; ++j) {
#pragma unroll
      for (int mm = 1; mm < 16; mm <<= 1) ssq[j] += __shfl_xor(ssq[j], mm);
    }
    if (l == 0) {
#pragma unroll
      for (int j = 0; j < 4; ++j) {
        int p = p0 + j * 16 + gid;
        scC[((size_t)slot * NB + bb) * NP + p] = 1.f / fmaxf(sqrtf(ssq[j]), 1e-10f);
      }
    }
  }
}

// ---------------------------------------------------------------- fused corr
// Stage one 8 KB fp8 supertile (contiguous in global) into LDS.
__device__ __forceinline__ void stage_sup(const unsigned long long* __restrict__ st,
                                          unsigned long long* buf, int tid) {
#pragma unroll
  for (int i = 0; i < 2; ++i) {
    const char* g = (const char*)st + (size_t)(i * 256 + tid) * 16;
    char* d = (char*)buf + i * 4096 + (tid & 192) * 16;
    __builtin_amdgcn_global_load_lds(
        (const __attribute__((address_space(1))) void*)g,
        (__attribute__((address_space(3))) void*)d, 16, 0, 0);
  }
}

// grid 4096 linear, decoded so id%8 == z%8: one z's 64 tile-blocks are
// temporally co-resident per XCD (L2-resident operands). Block 256 = 4 waves,
// each wave 64x64 (4x4 MFMA), fp8 e4m3 operands. Merged K-loop, BK=64.
//
// 2-phase prefetch schedule (T3 minimum form): double-buffered 64 KB LDS;
// issue tile kt+1's global_load_lds BEFORE computing tile kt, then one
// vmcnt(0)+s_barrier AFTER the MFMA cluster. Stage latency hides under
// ~32-64 MFMAs instead of being serially exposed at a pre-compute drain.
__global__ __launch_bounds__(256, 2) void corr_kernel(
    const unsigned long long* __restrict__ Fb,
    const unsigned long long* __restrict__ Cb,
    const float* __restrict__ scF, const float* __restrict__ scC,
    float* __restrict__ rowfd, float* __restrict__ rowrcd,
    float* __restrict__ cross) {
  __shared__ unsigned long long Afs[2][1024], Bfs[2][1024],
                                Acs[2][1024], Bcs[2][1024];  // 64 KB

  int id = blockIdx.x;
  int zl = id & 7, q = id >> 3;
  int bx = q & 7, by = (q >> 3) & 7, zh = q >> 6;
  int z = zh * 8 + zl;
  int h = z >> 4, bb = z & 15;
  int p0 = bx * 128, q0 = by * 128;
  int tid = threadIdx.x, ln = tid & 63, w = tid >> 6;
  int wm = w >> 1, wn = w & 1, quad = ln >> 4, t16 = ln & 15;

  const unsigned long long* AfB = Fb + (((size_t)bb * 12) * 8 + bx) * 1024;
  const unsigned long long* BfB = Fb + ((((size_t)h * NB + bb) * 12) * 8 + by) * 1024;
  const unsigned long long* AcB = Cb + (((size_t)bb * 8) * 8 + bx) * 1024;
  const unsigned long long* BcB = Cb + ((((size_t)h * NB + bb) * 8) * 8 + by) * 1024;
  const size_t KTSTR = (size_t)8 * 1024;  // one kt step = 8 supertiles

  f32x4 accf[4][4], accc[4][4];
#pragma unroll
  for (int i = 0; i < 4; ++i)
#pragma unroll
    for (int j = 0; j < 4; ++j) {
      accf[i][j] = (f32x4){0.f, 0.f, 0.f, 0.f};
      accc[i][j] = (f32x4){0.f, 0.f, 0.f, 0.f};
    }

  // prologue: stage kt=0 into set 0, drain, barrier.
  stage_sup(AfB, Afs[0], tid);
  stage_sup(BfB, Bfs[0], tid);
  stage_sup(AcB, Acs[0], tid);
  stage_sup(BcB, Bcs[0], tid);
  asm volatile("s_waitcnt vmcnt(0)" ::: "memory");
  __builtin_amdgcn_s_barrier();

  int cur = 0;
  for (int kt = 0; kt < 12; ++kt) {
    int nxt = cur ^ 1;
    // ---- issue next tile's stages (fly during this tile's compute)
    if (kt + 1 < 12) {
      stage_sup(AfB + (kt + 1) * KTSTR, Afs[nxt], tid);
      stage_sup(BfB + (kt + 1) * KTSTR, Bfs[nxt], tid);
      if (kt + 1 < 8) {
        stage_sup(AcB + (kt + 1) * KTSTR, Acs[nxt], tid);
        stage_sup(BcB + (kt + 1) * KTSTR, Bcs[nxt], tid);
      }
    }
    // ---- compute current tile
    const unsigned long long* Af = Afs[cur];
    const unsigned long long* Bf = Bfs[cur];
#pragma unroll
    for (int s = 0; s < 2; ++s) {
      long a[4], b[4];
#pragma unroll
      for (int mi = 0; mi < 4; ++mi)
        a[mi] = (long)Af[s * 512 + quad * 128 + wm * 64 + mi * 16 + t16];
#pragma unroll
      for (int ni = 0; ni < 4; ++ni)
        b[ni] = (long)Bf[s * 512 + quad * 128 + wn * 64 + ni * 16 + t16];
#pragma unroll
      for (int mi = 0; mi < 4; ++mi)
#pragma unroll
        for (int ni = 0; ni < 4; ++ni)
          accf[mi][ni] = __builtin_amdgcn_mfma_f32_16x16x32_fp8_fp8(
              a[mi], b[ni], accf[mi][ni], 0, 0, 0);
    }
    if (kt < 8) {
      const unsigned long long* Ac = Acs[cur];
      const unsigned long long* Bc = Bcs[cur];
#pragma unroll
      for (int s = 0; s < 2; ++s) {
        long a[4], b[4];
#pragma unroll
        for (int mi = 0; mi < 4; ++mi)
          a[mi] = (long)Ac[s * 512 + quad * 128 + wm * 64 + mi * 16 + t16];
#pragma unroll
        for (int ni = 0; ni < 4; ++ni)
          b[ni] = (long)Bc[s * 512 + quad * 128 + wn * 64 + ni * 16 + t16];
#pragma unroll
        for (int mi = 0; mi < 4; ++mi)
#pragma unroll
          for (int ni = 0; ni < 4; ++ni)
            accc[mi][ni] = __builtin_amdgcn_mfma_f32_16x16x32_fp8_fp8(
                a[mi], b[ni], accc[mi][ni], 0, 0, 0);
      }
    }
    // ---- single drain+barrier per iteration, AFTER compute:
    //  - this wave's kt+1 loads land (vmcnt 0), all waves' ds_reads of
    //    buf[cur] are complete (program order) -> safe to overwrite next iter.
    asm volatile("s_waitcnt vmcnt(0)" ::: "memory");
    __builtin_amdgcn_s_barrier();
    cur = nxt;
  }

  // ---- stage norm scales into LDS (reuse Afs)
  float* sm = (float*)Afs;
  {
    const float* s0 = scF + (size_t)bb * NP;
    const float* s1 = scF + ((size_t)h * NB + bb) * NP;
    const float* s2 = scC + (size_t)bb * NP;
    const float* s3 = scC + ((size_t)h * NB + bb) * NP;
    if (tid < 128) {
      sm[tid] = s0[p0 + tid];
      sm[256 + tid] = s2[p0 + tid];
    } else {
      int u = tid - 128;
      sm[128 + u] = s1[q0 + u];
      sm[384 + u] = s3[q0 + u];
    }
  }
  __syncthreads();

  // ---- epilogue: C/D layout row = quad*4 + reg, col = t16; apply scales
  float sbf[4], sbc[4];
#pragma unroll
  for (int ni = 0; ni < 4; ++ni) {
    int qq = wn * 64 + ni * 16 + t16;
    sbf[ni] = sm[128 + qq];
    sbc[ni] = sm[384 + qq];
  }
  float cross_l = 0.f;
#pragma unroll
  for (int mi = 0; mi < 4; ++mi) {
#pragma unroll
    for (int r = 0; r < 4; ++r) {
      int pl = wm * 64 + mi * 16 + quad * 4 + r;
      float saf = sm[pl], sac = sm[256 + pl];
      float sfd = 0.f, srw = 0.f;
#pragma unroll
      for (int ni = 0; ni < 4; ++ni) {
        float fd = accf[mi][ni][r] * (saf * sbf[ni]);
        float cd = accc[mi][ni][r] * (sac * sbc[ni]);
        float rc = fmaxf(cd, 0.f);
        sfd += fd;
        srw += rc;
        cross_l += rc * fd;
      }
#pragma unroll
      for (int mm = 1; mm < 16; mm <<= 1) {
        sfd += __shfl_xor(sfd, mm);
        srw += __shfl_xor(srw, mm);
      }
      if (t16 == 0) {
        int p = p0 + pl;
        size_t idx = ((size_t)h * NB + bb) * NP + p;
        atomicAdd(&rowfd[idx], sfd);
        atomicAdd(&rowrcd[idx], srw);
      }
    }
  }
#pragma unroll
  for (int mm = 1; mm < 64; mm <<= 1) cross_l += __shfl_xor(cross_l, mm);
  float* crs = (float*)Bfs;
  if (ln == 0) crs[w] = cross_l;
  __syncthreads();
  if (tid == 0) atomicAdd(&cross[h], crs[0] + crs[1] + crs[2] + crs[3]);
}

// ---------------------------------------------------------------- finalize
__global__ void finalize_partial(const float* __restrict__ rowfd,
                                 const float* __restrict__ rowrcd,
                                 const float* __restrict__ cross,
                                 float* __restrict__ losses) {
  __shared__ float r1[16], r2[16], r3[16];
  const float shifts[4] = {0.18f, 0.12f, 0.46f, 0.46f};
  int h = blockIdx.x, tid = threadIdx.x, w = tid >> 6, ln = tid & 63;
  float s1 = 0.f, s2 = 0.f, s3 = 0.f;
  for (int i = tid; i < NB * NP; i += 1024) {
    float a = rowfd[h * NB * NP + i];
    float c = rowrcd[h * NB * NP + i];
    s1 += a;
    s2 += c;
    s3 += a * c;
  }
#pragma unroll
  for (int mm = 1; mm < 64; mm <<= 1) {
    s1 += __shfl_xor(s1, mm);
    s2 += __shfl_xor(s2, mm);
    s3 += __shfl_xor(s3, mm);
  }
  if (ln == 0) { r1[w] = s1; r2[w] = s2; r3[w] = s3; }
  __syncthreads();
  if (tid == 0) {
    float Sfd = 0.f, Srcd = 0.f, Sdot = 0.f;
#pragma unroll
    for (int i = 0; i < 16; ++i) { Sfd += r1[i]; Srcd += r2[i]; Sdot += r3[i]; }
    losses[h] = -(cross[h] - Sdot * (1.0f / 1024.0f) +
                  (Sfd / NTOT - shifts[h]) * Srcd) / NTOT;
  }
}

__global__ void finalize_combine(const float* __restrict__ losses,
                                 float* __restrict__ out) {
  if (threadIdx.x == 0) {
    out[0] = losses[0];
    out[1] = losses[1];
    out[2] = 0.5f * (losses[2] + losses[3]);
  }
}

// ---------------------------------------------------------------- launch
extern "C" void kernel_launch(void* const* d_in, const int* in_sizes, int n_in,
                              void* d_out, int out_size, void* d_ws, size_t ws_size,
                              hipStream_t stream) {
  (void)in_sizes; (void)n_in; (void)out_size; (void)ws_size;
  const float* orig_feats = (const float*)d_in[0];
  const float* orig_feats_pos = (const float*)d_in[1];
  const float* orig_code = (const float*)d_in[4];
  const float* orig_code_pos = (const float*)d_in[5];
  const float* coords1 = (const float*)d_in[8];
  const float* coords2 = (const float*)d_in[9];
  const int* perms = (const int*)d_in[10];
  float* out = (float*)d_out;

  char* ws = (char*)d_ws;
  size_t off = 0;
  __hip_bfloat16* fTb = (__hip_bfloat16*)(ws + off); off += (size_t)2 * NB * HW * CF * 2;
  __hip_bfloat16* cTb = (__hip_bfloat16*)(ws + off); off += (size_t)2 * NB * HW * CC * 2;
  unsigned char* Fb = (unsigned char*)(ws + off); off += (size_t)4 * NB * NP * CF;  // fp8
  unsigned char* Cb = (unsigned char*)(ws + off); off += (size_t)4 * NB * NP * CC;  // fp8
  float* rowfd  = (float*)(ws + off); off += (size_t)4 * NB * NP * 4;
  float* rowrcd = (float*)(ws + off); off += (size_t)4 * NB * NP * 4;
  float* cross  = (float*)(ws + off); off += 64;
  float* losses = (float*)(ws + off); off += 64;
  float* scF    = (float*)(ws + off); off += (size_t)4 * NB * NP * 4;
  float* scC    = (float*)(ws + off); off += (size_t)4 * NB * NP * 4;

  // zero accumulators (rowfd | rowrcd | cross | losses contiguous)
  (void)hipMemsetAsync(rowfd, 0, (size_t)4 * NB * NP * 4 * 2 + 128, stream);

  dim3 tb(32, 8);
  transpose_bf16_kernel<<<dim3(25, 24, 32), tb, 0, stream>>>(
      orig_feats, orig_feats_pos, fTb, CF);
  transpose_bf16_kernel<<<dim3(25, 16, 32), tb, 0, stream>>>(
      orig_code, orig_code_pos, cTb, CC);
  sample_pack_kernel<<<dim3(16, 16, 4), 256, 0, stream>>>(
      fTb, cTb, coords1, coords2, perms, Fb, Cb, scF, scC);

  corr_kernel<<<dim3(4096), 256, 0, stream>>>(
      (const unsigned long long*)Fb, (const unsigned long long*)Cb,
      scF, scC, rowfd, rowrcd, cross);
  finalize_partial<<<4, 1024, 0, stream>>>(rowfd, rowrcd, cross, losses);
  finalize_combine<<<1, 64, 0, stream>>>(losses, out);
}